// Round 13
// baseline (85.345 us; speedup 1.0000x reference)
//
#include <hip/hip_runtime.h>
#include <cstdint>
#include <cstddef>

#define N_PATH 14
#define NEG_SLOPE 0.2f
#define BINW 128
#define NZ2 4          // layer-2 K-split (partial buffers)
#define PBLK 32        // k_prep grid (small -> cheap grid barrier)
#define PTHR 512

using u16 = unsigned short;
using u32 = unsigned int;
typedef __attribute__((ext_vector_type(4))) float f32x4;
typedef __attribute__((ext_vector_type(8))) short bf16x8;

__device__ __forceinline__ float lrelu(float v) { return v > 0.f ? v : NEG_SLOPE * v; }
__device__ __forceinline__ u16 f2bf(float f) {
    union { float f; u32 u; } c; c.f = f;
    return (u16)((c.u + 0x7FFFu + ((c.u >> 16) & 1u)) >> 16);
}
__device__ __forceinline__ float bf2f(u16 v) {
    union { u32 u; float f; } c; c.u = ((u32)v) << 16; return c.f;
}
__device__ __forceinline__ int imin(int a, int b) { return a < b ? a : b; }

// ------------------------------------------------------------------
// Device-wide barrier (r8-proven logic; cheap at 32 blocks).
// ------------------------------------------------------------------
__device__ __forceinline__ void gridbar(unsigned* bar, unsigned& mygen)
{
    __syncthreads();
    if (threadIdx.x == 0) {
        __threadfence();
        unsigned nblk = gridDim.x;
        unsigned prev = atomicAdd(&bar[0], 1u);
        if (prev == nblk - 1u) {
            atomicExch(&bar[0], 0u);
            __threadfence();
            atomicAdd(&bar[1], 1u);
        } else {
            unsigned g;
            do {
                __builtin_amdgcn_s_sleep(8);
                g = __hip_atomic_load(&bar[1], __ATOMIC_RELAXED, __HIP_MEMORY_SCOPE_AGENT);
            } while (g == mygen);
        }
        mygen++;
        __threadfence();
    }
    __syncthreads();
}

// ------------------------------------------------------------------
// k_prep: build2-scan -> gridbar -> build1-scan + wave-coop gather.
// Map encoding: 0 = empty, -2 = claimed (transient), idx+1 = assigned.
// Control zone (mapB,mapC,cnt,bar,deg2,deg1) pre-zeroed by one memset.
// cnt[0]=nB, cnt[1]=nC.
// ------------------------------------------------------------------
__global__ __launch_bounds__(PTHR)
void k_prep(const int* __restrict__ esrc, const int* __restrict__ edst,
            int E, int Nn, const float* __restrict__ x,
            int* __restrict__ mapB, int* __restrict__ mapC,
            int* __restrict__ cnt, unsigned* __restrict__ bar,
            int* __restrict__ deg2, int* __restrict__ deg1,
            int* __restrict__ listB, int* __restrict__ e2bin,
            int* __restrict__ e1bin, u16* __restrict__ Abf,
            int capB, int capC)
{
    unsigned mygen = 0;
    int gtid = blockIdx.x * blockDim.x + threadIdx.x;
    int gstride = gridDim.x * blockDim.x;
    int ET = E + Nn;
    int lane = threadIdx.x & 63;

    // ---- P1: A-frontier (dst < N_PATH) ----
    for (int e = gtid; e < ET; e += gstride) {
        int s, d;
        if (e < E) { s = esrc[e]; d = edst[e]; } else { s = e - E; d = s; }
        if (d >= N_PATH) continue;
        int slot = atomicAdd(&deg2[d], 1);
        if (slot < BINW) e2bin[d * BINW + slot] = s;
        int old = atomicCAS(&mapB[s], 0, -2);
        if (old == 0) {
            int idx = atomicAdd(&cnt[0], 1);
            if (idx < capB) listB[idx] = s;
            mapB[s] = idx + 1;
        }
    }
    gridbar(bar, mygen);

    // ---- P2: B-frontier + wave-cooperative gather ----
    int niter = (ET + gstride - 1) / gstride;
    for (int it = 0; it < niter; ++it) {
        int e = gtid + it * gstride;
        int s = 0, idx = -1;
        if (e < ET) {
            int d;
            if (e < E) { s = esrc[e]; d = edst[e]; } else { s = e - E; d = s; }
            int bv = mapB[d];
            if (bv >= 1 && bv <= capB) {
                int b = bv - 1;
                int slot = atomicAdd(&deg1[b], 1);
                if (slot < BINW) e1bin[b * BINW + slot] = s;
                int old = atomicCAS(&mapC[s], 0, -2);
                if (old == 0) {
                    idx = atomicAdd(&cnt[1], 1);
                    mapC[s] = idx + 1;
                }
            }
        }
        bool win = (idx >= 0 && idx < capC);
        unsigned long long mask = __ballot(win);
        while (mask) {
            int l = (int)(__ffsll((long long)mask) - 1);
            mask &= mask - 1;
            int wnode = __shfl(s, l);
            int wslot = __shfl(idx, l);
            const float* xr = x + (size_t)wnode * 768 + lane * 12;
            u16* dst = Abf + (size_t)wslot * 768 + lane * 12;
            float4 v0 = *reinterpret_cast<const float4*>(xr);
            float4 v1 = *reinterpret_cast<const float4*>(xr + 4);
            float4 v2 = *reinterpret_cast<const float4*>(xr + 8);
            uint2 o0, o1, o2;
            o0.x = (u32)f2bf(v0.x) | ((u32)f2bf(v0.y) << 16);
            o0.y = (u32)f2bf(v0.z) | ((u32)f2bf(v0.w) << 16);
            o1.x = (u32)f2bf(v1.x) | ((u32)f2bf(v1.y) << 16);
            o1.y = (u32)f2bf(v1.z) | ((u32)f2bf(v1.w) << 16);
            o2.x = (u32)f2bf(v2.x) | ((u32)f2bf(v2.y) << 16);
            o2.y = (u32)f2bf(v2.z) | ((u32)f2bf(v2.w) << 16);
            *reinterpret_cast<uint2*>(dst)     = o0;
            *reinterpret_cast<uint2*>(dst + 4) = o1;
            *reinterpret_cast<uint2*>(dst + 8) = o2;
        }
    }
}

// ------------------------------------------------------------------
// Stage a 32-col x 768-K strip of f32 W (k-major) into LDS as bf16,
// XOR-swizzled per 64-k chunk.
// ------------------------------------------------------------------
__device__ __forceinline__
void stage_W(const float* __restrict__ W, int ldw, int wKoff, int n0,
             u16* __restrict__ Ws, int nthreads)
{
    int t = threadIdx.x;
    for (int idx = t; idx < 768 * 8; idx += nthreads) {
        int n4 = (idx & 7) << 2;
        int k  = idx >> 3;
        float4 wv = *reinterpret_cast<const float4*>(
            W + (size_t)(wKoff + k) * ldw + n0 + n4);
        int c = (k >> 3) & 7, kl = k & 7;
        int chbase = (k >> 6) * 2048;
        float wa[4] = {wv.x, wv.y, wv.z, wv.w};
        #pragma unroll
        for (int i = 0; i < 4; ++i) {
            int n = n4 + i;
            Ws[chbase + n * 64 + (kl | ((c ^ (n & 7)) << 3))] = f2bf(wa[i]);
        }
    }
}

// ------------------------------------------------------------------
// Layer-1 GEMM: barrier-free main loop (r12-proven).
// ------------------------------------------------------------------
__global__ __launch_bounds__(512)
void k_gemm1(const u16* __restrict__ Abf,
             const int* __restrict__ listB, const int* __restrict__ mapC,
             const float* __restrict__ Wl1, const float* __restrict__ Wr1,
             const float* __restrict__ bl1, const float* __restrict__ br1,
             u16* __restrict__ XL1, u16* __restrict__ XR1,
             const int* __restrict__ cnt, int capC, int capB)
{
    __shared__ __align__(16) u16 Ws[12 * 2048];   // 48 KB
    int blk = blockIdx.x;            // 0..191
    bool isR = blk >= 96;
    int n0 = (isR ? blk - 96 : blk) * 32;
    const float* W    = isR ? Wr1 : Wl1;
    const float* bias = isR ? br1 : bl1;
    u16* Cout = isR ? XR1 : XL1;
    int nC = imin(cnt[1], capC);
    int M  = isR ? imin(cnt[0], capB) : nC;

    stage_W(W, 3072, 0, n0, Ws, 512);
    __syncthreads();

    int t = threadIdx.x;
    int wave = t >> 6, lane = t & 63;
    int lrow = lane & 15, lhi = lane >> 4;
    int x0 = lrow & 7;
    int preB0 = lrow * 64;
    int preB1 = (16 + lrow) * 64;

    float bv0 = bias[n0 + lrow];
    float bv1 = bias[n0 + 16 + lrow];

    int ntiles = (M + 63) >> 6;
    for (int rt = wave; rt < ntiles; rt += 8) {
        const u16* ap0; const u16* ap1; const u16* ap2; const u16* ap3;
        {
            int ar0 = rt * 64 + lrow;       if (ar0 >= M) ar0 = M - 1;
            int ar1 = ar0 + 16;             if (ar1 >= M) ar1 = M - 1;
            int ar2 = rt * 64 + 32 + lrow;  if (ar2 >= M) ar2 = M - 1;
            int ar3 = ar2 + 16;             if (ar3 >= M) ar3 = M - 1;
            int g0 = ar0, g1 = ar1, g2 = ar2, g3 = ar3;
            if (isR) {
                g0 = mapC[listB[ar0]] - 1; if (g0 < 0) g0 = 0; if (g0 >= nC) g0 = nC - 1;
                g1 = mapC[listB[ar1]] - 1; if (g1 < 0) g1 = 0; if (g1 >= nC) g1 = nC - 1;
                g2 = mapC[listB[ar2]] - 1; if (g2 < 0) g2 = 0; if (g2 >= nC) g2 = nC - 1;
                g3 = mapC[listB[ar3]] - 1; if (g3 < 0) g3 = 0; if (g3 >= nC) g3 = nC - 1;
            }
            ap0 = Abf + (size_t)g0 * 768 + lhi * 8;
            ap1 = Abf + (size_t)g1 * 768 + lhi * 8;
            ap2 = Abf + (size_t)g2 * 768 + lhi * 8;
            ap3 = Abf + (size_t)g3 * 768 + lhi * 8;
        }

        f32x4 acc00 = {0,0,0,0}, acc01 = {0,0,0,0};
        f32x4 acc10 = {0,0,0,0}, acc11 = {0,0,0,0};
        f32x4 acc20 = {0,0,0,0}, acc21 = {0,0,0,0};
        f32x4 acc30 = {0,0,0,0}, acc31 = {0,0,0,0};

        #pragma unroll 4
        for (int kst = 0; kst < 24; ++kst) {
            int ch = kst >> 1;
            int sw = ((((kst & 1) << 2) | lhi) ^ x0) << 3;
            bf16x8 b0 = *reinterpret_cast<const bf16x8*>(&Ws[ch * 2048 + preB0 + sw]);
            bf16x8 b1 = *reinterpret_cast<const bf16x8*>(&Ws[ch * 2048 + preB1 + sw]);
            bf16x8 a0 = *reinterpret_cast<const bf16x8*>(ap0 + kst * 32);
            bf16x8 a1 = *reinterpret_cast<const bf16x8*>(ap1 + kst * 32);
            bf16x8 a2 = *reinterpret_cast<const bf16x8*>(ap2 + kst * 32);
            bf16x8 a3 = *reinterpret_cast<const bf16x8*>(ap3 + kst * 32);
            acc00 = __builtin_amdgcn_mfma_f32_16x16x32_bf16(a0, b0, acc00, 0, 0, 0);
            acc01 = __builtin_amdgcn_mfma_f32_16x16x32_bf16(a0, b1, acc01, 0, 0, 0);
            acc10 = __builtin_amdgcn_mfma_f32_16x16x32_bf16(a1, b0, acc10, 0, 0, 0);
            acc11 = __builtin_amdgcn_mfma_f32_16x16x32_bf16(a1, b1, acc11, 0, 0, 0);
            acc20 = __builtin_amdgcn_mfma_f32_16x16x32_bf16(a2, b0, acc20, 0, 0, 0);
            acc21 = __builtin_amdgcn_mfma_f32_16x16x32_bf16(a2, b1, acc21, 0, 0, 0);
            acc30 = __builtin_amdgcn_mfma_f32_16x16x32_bf16(a3, b0, acc30, 0, 0, 0);
            acc31 = __builtin_amdgcn_mfma_f32_16x16x32_bf16(a3, b1, acc31, 0, 0, 0);
        }

        int gc0 = n0 + lrow, gc1 = n0 + 16 + lrow;
        #pragma unroll
        for (int j = 0; j < 4; ++j) {
            int r0 = rt * 64 + lhi * 4 + j;
            int r1 = r0 + 16, r2 = r0 + 32, r3 = r0 + 48;
            if (r0 < M) {
                Cout[(size_t)r0 * 3072 + gc0] = f2bf(acc00[j] + bv0);
                Cout[(size_t)r0 * 3072 + gc1] = f2bf(acc01[j] + bv1);
            }
            if (r1 < M) {
                Cout[(size_t)r1 * 3072 + gc0] = f2bf(acc10[j] + bv0);
                Cout[(size_t)r1 * 3072 + gc1] = f2bf(acc11[j] + bv1);
            }
            if (r2 < M) {
                Cout[(size_t)r2 * 3072 + gc0] = f2bf(acc20[j] + bv0);
                Cout[(size_t)r2 * 3072 + gc1] = f2bf(acc21[j] + bv1);
            }
            if (r3 < M) {
                Cout[(size_t)r3 * 3072 + gc0] = f2bf(acc30[j] + bv0);
                Cout[(size_t)r3 * 3072 + gc1] = f2bf(acc31[j] + bv1);
            }
        }
    }
}

// ------------------------------------------------------------------
// Layer-2 GEMM: same scheme; grid = 48 col-strips x NZ2 k-windows.
// ------------------------------------------------------------------
__global__ __launch_bounds__(256)
void k_gemm2(const u16* __restrict__ H1bf,
             const float* __restrict__ Wl2, const float* __restrict__ Wr2,
             float* __restrict__ XLR2,
             const int* __restrict__ cnt, int capB)
{
    __shared__ __align__(16) u16 Ws[12 * 2048];
    int strip = blockIdx.x;
    int z = blockIdx.z;
    int n0g = strip * 32;
    bool hi = n0g >= 768;
    const float* W = hi ? Wr2 : Wl2;
    int n0w = hi ? n0g - 768 : n0g;
    int nB = imin(cnt[0], capB);
    float* Cp = XLR2 + (size_t)z * capB * 1536;

    stage_W(W, 768, z * 768, n0w, Ws, 256);
    __syncthreads();

    int t = threadIdx.x;
    int wave = t >> 6, lane = t & 63;
    int lrow = lane & 15, lhi = lane >> 4;
    int x0 = lrow & 7;
    int preB0 = lrow * 64, preB1 = (16 + lrow) * 64;

    int ntiles = (nB + 31) >> 5;
    for (int rt = wave; rt < ntiles; rt += 4) {
        int ar0 = rt * 32 + lrow;  if (ar0 >= nB) ar0 = nB - 1;
        int ar1 = ar0 + 16;        if (ar1 >= nB) ar1 = nB - 1;
        const u16* ap0 = H1bf + (size_t)ar0 * 3072 + z * 768 + lhi * 8;
        const u16* ap1 = H1bf + (size_t)ar1 * 3072 + z * 768 + lhi * 8;

        f32x4 acc00 = {0,0,0,0}, acc01 = {0,0,0,0};
        f32x4 acc10 = {0,0,0,0}, acc11 = {0,0,0,0};

        #pragma unroll 4
        for (int kst = 0; kst < 24; ++kst) {
            int ch = kst >> 1;
            int sw = ((((kst & 1) << 2) | lhi) ^ x0) << 3;
            bf16x8 b0 = *reinterpret_cast<const bf16x8*>(&Ws[ch * 2048 + preB0 + sw]);
            bf16x8 b1 = *reinterpret_cast<const bf16x8*>(&Ws[ch * 2048 + preB1 + sw]);
            bf16x8 a0 = *reinterpret_cast<const bf16x8*>(ap0 + kst * 32);
            bf16x8 a1 = *reinterpret_cast<const bf16x8*>(ap1 + kst * 32);
            acc00 = __builtin_amdgcn_mfma_f32_16x16x32_bf16(a0, b0, acc00, 0, 0, 0);
            acc01 = __builtin_amdgcn_mfma_f32_16x16x32_bf16(a0, b1, acc01, 0, 0, 0);
            acc10 = __builtin_amdgcn_mfma_f32_16x16x32_bf16(a1, b0, acc10, 0, 0, 0);
            acc11 = __builtin_amdgcn_mfma_f32_16x16x32_bf16(a1, b1, acc11, 0, 0, 0);
        }

        int gc0 = n0g + lrow, gc1 = n0g + 16 + lrow;
        #pragma unroll
        for (int j = 0; j < 4; ++j) {
            int r0 = rt * 32 + lhi * 4 + j;
            int r1 = r0 + 16;
            if (r0 < nB) {
                Cp[(size_t)r0 * 1536 + gc0] = acc00[j];
                Cp[(size_t)r0 * 1536 + gc1] = acc01[j];
            }
            if (r1 < nB) {
                Cp[(size_t)r1 * 1536 + gc0] = acc10[j];
                Cp[(size_t)r1 * 1536 + gc1] = acc11[j];
            }
        }
    }
}

// ------------------------------------------------------------------
// Fused layer-1 edge phase: one block per B node, 4 waves = 4 heads.
// ------------------------------------------------------------------
__global__ __launch_bounds__(256)
void k_fused1(const u16* __restrict__ XL1, const u16* __restrict__ XR1,
              const float* __restrict__ att1, const float* __restrict__ bias1,
              const int* __restrict__ mapC,
              const int* __restrict__ deg1, const int* __restrict__ e1bin,
              u16* __restrict__ H1bf,
              const int* __restrict__ cnt, int capB, int capC)
{
    __shared__ int sIdx[BINW];
    int b = blockIdx.x;
    int nB = cnt[0]; if (nB > capB) nB = capB;
    if (b >= nB) return;
    int t = threadIdx.x;
    int n = deg1[b]; if (n > BINW) n = BINW;
    if (t < n) {
        int c = mapC[e1bin[b * BINW + t]] - 1;
        if (c < 0) c = 0; if (c >= capC) c = capC - 1;
        sIdx[t] = c;
    }
    __syncthreads();

    int base = t * 12;
    float xr[12], av[12];
    {
        const u16* p = XR1 + (size_t)b * 3072 + base;
        uint2 q0 = *reinterpret_cast<const uint2*>(p);
        uint2 q1 = *reinterpret_cast<const uint2*>(p + 4);
        uint2 q2 = *reinterpret_cast<const uint2*>(p + 8);
        u32 w[6] = {q0.x, q0.y, q1.x, q1.y, q2.x, q2.y};
        #pragma unroll
        for (int j = 0; j < 6; ++j) {
            xr[2*j]   = bf2f((u16)(w[j] & 0xFFFF));
            xr[2*j+1] = bf2f((u16)(w[j] >> 16));
        }
        float4 a0 = *reinterpret_cast<const float4*>(att1 + base);
        float4 a1 = *reinterpret_cast<const float4*>(att1 + base + 4);
        float4 a2 = *reinterpret_cast<const float4*>(att1 + base + 8);
        av[0]=a0.x; av[1]=a0.y; av[2]=a0.z; av[3]=a0.w;
        av[4]=a1.x; av[5]=a1.y; av[6]=a1.z; av[7]=a1.w;
        av[8]=a2.x; av[9]=a2.y; av[10]=a2.z; av[11]=a2.w;
    }

    float acc[12];
    #pragma unroll
    for (int j = 0; j < 12; ++j) acc[j] = 0.f;
    float sumex = 0.f;

    uint2 q0, q1, q2;
    if (n > 0) {
        const u16* p = XL1 + (size_t)sIdx[0] * 3072 + base;
        q0 = *reinterpret_cast<const uint2*>(p);
        q1 = *reinterpret_cast<const uint2*>(p + 4);
        q2 = *reinterpret_cast<const uint2*>(p + 8);
    }
    for (int i = 0; i < n; ++i) {
        uint2 r0 = q0, r1 = q1, r2 = q2;
        if (i + 1 < n) {
            const u16* p = XL1 + (size_t)sIdx[i + 1] * 3072 + base;
            q0 = *reinterpret_cast<const uint2*>(p);
            q1 = *reinterpret_cast<const uint2*>(p + 4);
            q2 = *reinterpret_cast<const uint2*>(p + 8);
        }
        float xl[12];
        u32 w[6] = {r0.x, r0.y, r1.x, r1.y, r2.x, r2.y};
        #pragma unroll
        for (int j = 0; j < 6; ++j) {
            xl[2*j]   = bf2f((u16)(w[j] & 0xFFFF));
            xl[2*j+1] = bf2f((u16)(w[j] >> 16));
        }
        float pa = 0.f;
        #pragma unroll
        for (int j = 0; j < 12; ++j)
            pa = fmaf(av[j], lrelu(xl[j] + xr[j]), pa);
        #pragma unroll
        for (int off = 32; off > 0; off >>= 1) pa += __shfl_xor(pa, off);
        float ex = expf(pa);
        sumex += ex;
        #pragma unroll
        for (int j = 0; j < 12; ++j) acc[j] = fmaf(ex, xl[j], acc[j]);
    }

    float inv = 1.f / (sumex + 1e-16f);
    u32 o[6];
    #pragma unroll
    for (int j = 0; j < 6; ++j) {
        float v0 = acc[2*j]   * inv + bias1[base + 2*j];
        float v1 = acc[2*j+1] * inv + bias1[base + 2*j+1];
        v0 = v0 > 0.f ? v0 : 0.f;
        v1 = v1 > 0.f ? v1 : 0.f;
        o[j] = (u32)f2bf(v0) | ((u32)f2bf(v1) << 16);
    }
    u16* q = H1bf + (size_t)b * 3072 + base;
    uint2 s0; s0.x = o[0]; s0.y = o[1];
    uint2 s1; s1.x = o[2]; s1.y = o[3];
    uint2 s2; s2.x = o[4]; s2.y = o[5];
    *reinterpret_cast<uint2*>(q)     = s0;
    *reinterpret_cast<uint2*>(q + 4) = s1;
    *reinterpret_cast<uint2*>(q + 8) = s2;
}

// ------------------------------------------------------------------
// Fused layer-2 edge phase: one block per pathology node, 4 waves split
// edges, LDS combine. Sums NZ2 K-partials + folded biases. Writes d_out.
// ------------------------------------------------------------------
__global__ __launch_bounds__(256)
void k_fused2(const float* __restrict__ XLR2,
              const float* __restrict__ att2, const float* __restrict__ bias2,
              const float* __restrict__ bl2, const float* __restrict__ br2,
              const int* __restrict__ mapB,
              const int* __restrict__ deg2, const int* __restrict__ e2bin,
              float* __restrict__ out, int capB)
{
    __shared__ int sIdx[BINW];
    __shared__ float sAcc[4][768];
    __shared__ float sSum[4];
    const size_t PART = (size_t)capB * 1536;
    int a = blockIdx.x;
    int t = threadIdx.x;
    int wv = t >> 6, lane = t & 63;
    int n = deg2[a]; if (n > BINW) n = BINW;
    if (t < n) {
        int bs = mapB[e2bin[a * BINW + t]] - 1;
        if (bs < 0) bs = 0; if (bs >= capB) bs = capB - 1;
        sIdx[t] = bs;
    }
    __syncthreads();

    int base = lane * 12;
    int bd = mapB[a] - 1;
    if (bd < 0) bd = 0; if (bd >= capB) bd = capB - 1;

    float xr[12], av[12], blv[12];
    {
        const float* p = XLR2 + (size_t)bd * 1536 + 768 + base;
        #pragma unroll
        for (int j = 0; j < 12; ++j) xr[j] = br2[base + j];
        for (int z = 0; z < NZ2; ++z)
            #pragma unroll
            for (int j = 0; j < 12; ++j) xr[j] += p[z * PART + j];
        #pragma unroll
        for (int j = 0; j < 12; ++j) { av[j] = att2[base + j]; blv[j] = bl2[base + j]; }
    }

    float acc[12];
    #pragma unroll
    for (int j = 0; j < 12; ++j) acc[j] = 0.f;
    float sumex = 0.f;

    for (int i = wv; i < n; i += 4) {
        int bs = sIdx[i];
        const float* p = XLR2 + (size_t)bs * 1536 + base;
        float xl[12];
        #pragma unroll
        for (int j = 0; j < 12; ++j) xl[j] = blv[j];
        for (int z = 0; z < NZ2; ++z)
            #pragma unroll
            for (int j = 0; j < 12; ++j) xl[j] += p[z * PART + j];
        float pa = 0.f;
        #pragma unroll
        for (int j = 0; j < 12; ++j)
            pa = fmaf(av[j], lrelu(xl[j] + xr[j]), pa);
        #pragma unroll
        for (int off = 32; off > 0; off >>= 1) pa += __shfl_xor(pa, off);
        float ex = expf(pa);
        sumex += ex;
        #pragma unroll
        for (int j = 0; j < 12; ++j) acc[j] = fmaf(ex, xl[j], acc[j]);
    }

    if (lane == 0) sSum[wv] = sumex;
    #pragma unroll
    for (int j = 0; j < 12; ++j) sAcc[wv][base + j] = acc[j];
    __syncthreads();

    float tot = sSum[0] + sSum[1] + sSum[2] + sSum[3];
    float inv = 1.f / (tot + 1e-16f);
    for (int c = t; c < 768; c += 256) {
        float s = sAcc[0][c] + sAcc[1][c] + sAcc[2][c] + sAcc[3][c];
        out[(size_t)a * 768 + c] = s * inv + bias2[c];
    }
}

// ------------------------------------------------------------------
// Host side
// ------------------------------------------------------------------
struct Lay {
    size_t zero, zeroBytes;                     // one contiguous memset-0 zone
    size_t mapB, mapC, cnt, bar, deg2, deg1;    // inside zero zone
    size_t listB, e1bin, e2bin;
    size_t Abf, XL1, XR1, H1bf, XLR2;
    size_t total;
};

static Lay makeLayout(int Nn, int cB, int cC)
{
    Lay L{};
    size_t off = 0;
    auto take = [&](size_t bytes) { size_t o = (off + 255) & ~(size_t)255; off = o + bytes; return o; };
    size_t zb = (size_t)(2 * Nn + 16 + 16 + 64 + cB) * 4;
    L.zero = take(zb); L.zeroBytes = zb;
    L.mapB = L.zero;
    L.mapC = L.mapB + (size_t)Nn * 4;
    L.cnt  = L.mapC + (size_t)Nn * 4;
    L.bar  = L.cnt + 16 * 4;
    L.deg2 = L.bar + 16 * 4;
    L.deg1 = L.deg2 + 64 * 4;
    L.listB = take((size_t)cB * 4);
    L.e1bin = take((size_t)cB * BINW * 4);
    L.e2bin = take((size_t)16 * BINW * 4);
    L.Abf  = take((size_t)cC * 768 * 2);
    L.XL1  = take((size_t)cC * 3072 * 2);
    L.XR1  = take((size_t)cB * 3072 * 2);
    L.H1bf = take((size_t)cB * 3072 * 2);
    L.XLR2 = take((size_t)NZ2 * cB * 1536 * 4);
    L.total = off;
    return L;
}

extern "C" void kernel_launch(void* const* d_in, const int* in_sizes, int n_in,
                              void* d_out, int out_size, void* d_ws, size_t ws_size,
                              hipStream_t stream)
{
    const float* x     = (const float*)d_in[0];
    const int*   ei    = (const int*)  d_in[1];
    const float* Wl1   = (const float*)d_in[2];
    const float* bl1   = (const float*)d_in[3];
    const float* Wr1   = (const float*)d_in[4];
    const float* br1   = (const float*)d_in[5];
    const float* att1  = (const float*)d_in[6];
    const float* bias1 = (const float*)d_in[7];
    const float* Wl2   = (const float*)d_in[8];
    const float* bl2   = (const float*)d_in[9];
    const float* Wr2   = (const float*)d_in[10];
    const float* br2   = (const float*)d_in[11];
    const float* att2  = (const float*)d_in[12];
    const float* bias2 = (const float*)d_in[13];
    float* out = (float*)d_out;

    int Nn = in_sizes[0] / 768;
    int E  = in_sizes[1] / 2;
    const int* esrc = ei;
    const int* edst = ei + E;

    static const int tiers[2][2] = { {256, 1024}, {128, 768} };
    int capB = tiers[1][0], capC = tiers[1][1];
    Lay L = makeLayout(Nn, capB, capC);
    for (int t = 0; t < 2; ++t) {
        Lay cand = makeLayout(Nn, tiers[t][0], tiers[t][1]);
        if (cand.total <= ws_size) { capB = tiers[t][0]; capC = tiers[t][1]; L = cand; break; }
    }

    char* ws = (char*)d_ws;
    int*      mapB  = (int*)     (ws + L.mapB);
    int*      mapC  = (int*)     (ws + L.mapC);
    int*      cnt   = (int*)     (ws + L.cnt);
    unsigned* bar   = (unsigned*)(ws + L.bar);
    int*      deg2  = (int*)     (ws + L.deg2);
    int*      deg1  = (int*)     (ws + L.deg1);
    int*      listB = (int*)     (ws + L.listB);
    int*      e1bin = (int*)     (ws + L.e1bin);
    int*      e2bin = (int*)     (ws + L.e2bin);
    u16*      Abf   = (u16*)     (ws + L.Abf);
    u16*      XL1   = (u16*)     (ws + L.XL1);
    u16*      XR1   = (u16*)     (ws + L.XR1);
    u16*      H1bf  = (u16*)     (ws + L.H1bf);
    float*    XLR2  = (float*)   (ws + L.XLR2);

    // one memset clears mapB/mapC (0 = empty sentinel), cnt, bar, deg2, deg1
    hipMemsetAsync(ws + L.zero, 0, L.zeroBytes, stream);

    k_prep<<<PBLK, PTHR, 0, stream>>>(esrc, edst, E, Nn, x,
                                      mapB, mapC, cnt, bar, deg2, deg1,
                                      listB, e2bin, e1bin, Abf, capB, capC);

    k_gemm1<<<192, 512, 0, stream>>>(Abf, listB, mapC, Wl1, Wr1, bl1, br1,
                                     XL1, XR1, cnt, capC, capB);

    k_fused1<<<capB, 256, 0, stream>>>(XL1, XR1, att1, bias1, mapC, deg1, e1bin,
                                       H1bf, cnt, capB, capC);

    k_gemm2<<<dim3(48, 1, NZ2), 256, 0, stream>>>(H1bf, Wl2, Wr2, XLR2, cnt, capB);

    k_fused2<<<N_PATH, 256, 0, stream>>>(XLR2, att2, bias2, bl2, br2, mapB,
                                         deg2, e2bin, out, capB);
}

// Round 14
// 75.512 us; speedup vs baseline: 1.1302x; 1.1302x over previous
//
#include <hip/hip_runtime.h>
#include <cstdint>
#include <cstddef>

#define N_PATH 14
#define NEG_SLOPE 0.2f
#define BINW 128
#define NZ2 4          // layer-2 K-split (partial buffers)

using u16 = unsigned short;
using u32 = unsigned int;
typedef __attribute__((ext_vector_type(4))) float f32x4;
typedef __attribute__((ext_vector_type(8))) short bf16x8;

__device__ __forceinline__ float lrelu(float v) { return v > 0.f ? v : NEG_SLOPE * v; }
__device__ __forceinline__ u16 f2bf(float f) {
    union { float f; u32 u; } c; c.f = f;
    return (u16)((c.u + 0x7FFFu + ((c.u >> 16) & 1u)) >> 16);
}
__device__ __forceinline__ float bf2f(u16 v) {
    union { u32 u; float f; } c; c.u = ((u32)v) << 16; return c.f;
}
__device__ __forceinline__ int imin(int a, int b) { return a < b ? a : b; }

// ------------------------------------------------------------------
// Init: mapB/mapC = -1; zero cnt/deg2/deg1
// ------------------------------------------------------------------
__global__ void k_init(int* __restrict__ mapBC, int nMap,
                       u32* __restrict__ z, int nZ)
{
    int stride = gridDim.x * blockDim.x;
    int i0 = blockIdx.x * blockDim.x + threadIdx.x;
    for (int i = i0; i < nMap; i += stride) mapBC[i] = -1;
    for (int i = i0; i < nZ; i += stride) z[i] = 0;
}

// ------------------------------------------------------------------
// Frontier building. cnt[0]=nB, cnt[1]=nC
// ------------------------------------------------------------------
__global__ void k_build2(const int* __restrict__ esrc, const int* __restrict__ edst,
                         int E, int Nn,
                         int* __restrict__ mapB, int* __restrict__ listB,
                         int* __restrict__ cnt,
                         int* __restrict__ deg2, int* __restrict__ e2bin,
                         int capB)
{
    int e = blockIdx.x * blockDim.x + threadIdx.x;
    int ET = E + Nn;
    if (e >= ET) return;
    int s, d;
    if (e < E) { s = esrc[e]; d = edst[e]; } else { s = e - E; d = s; }
    if (d >= N_PATH) return;
    int slot = atomicAdd(&deg2[d], 1);
    if (slot < BINW) e2bin[d * BINW + slot] = s;
    int old = atomicCAS(&mapB[s], -1, -2);
    if (old == -1) {
        int idx = atomicAdd(&cnt[0], 1);
        if (idx < capB) listB[idx] = s;
        mapB[s] = idx;
    }
}

// build1 + WAVE-COOPERATIVE gather (r12-proven).
__global__ void k_build1(const int* __restrict__ esrc, const int* __restrict__ edst,
                         int E, int Nn, const float* __restrict__ x,
                         const int* __restrict__ mapB,
                         int* __restrict__ mapC,
                         int* __restrict__ cnt,
                         int* __restrict__ deg1, int* __restrict__ e1bin,
                         u16* __restrict__ Abf,
                         int capB, int capC)
{
    int e = blockIdx.x * blockDim.x + threadIdx.x;
    int ET = E + Nn;
    int lane = threadIdx.x & 63;

    int s = 0;
    int idx = -1;
    if (e < ET) {
        int d;
        if (e < E) { s = esrc[e]; d = edst[e]; } else { s = e - E; d = s; }
        int b = mapB[d];
        if (b >= 0 && b < capB) {
            int slot = atomicAdd(&deg1[b], 1);
            if (slot < BINW) e1bin[b * BINW + slot] = s;
            int old = atomicCAS(&mapC[s], -1, -2);
            if (old == -1) {
                idx = atomicAdd(&cnt[1], 1);
                mapC[s] = idx;
            }
        }
    }

    bool win = (idx >= 0 && idx < capC);
    unsigned long long mask = __ballot(win);
    while (mask) {
        int l = (int)(__ffsll((long long)mask) - 1);
        mask &= mask - 1;
        int wnode = __shfl(s, l);
        int wslot = __shfl(idx, l);
        const float* xr = x + (size_t)wnode * 768 + lane * 12;
        u16* dst = Abf + (size_t)wslot * 768 + lane * 12;
        float4 v0 = *reinterpret_cast<const float4*>(xr);
        float4 v1 = *reinterpret_cast<const float4*>(xr + 4);
        float4 v2 = *reinterpret_cast<const float4*>(xr + 8);
        uint2 o0, o1, o2;
        o0.x = (u32)f2bf(v0.x) | ((u32)f2bf(v0.y) << 16);
        o0.y = (u32)f2bf(v0.z) | ((u32)f2bf(v0.w) << 16);
        o1.x = (u32)f2bf(v1.x) | ((u32)f2bf(v1.y) << 16);
        o1.y = (u32)f2bf(v1.z) | ((u32)f2bf(v1.w) << 16);
        o2.x = (u32)f2bf(v2.x) | ((u32)f2bf(v2.y) << 16);
        o2.y = (u32)f2bf(v2.z) | ((u32)f2bf(v2.w) << 16);
        *reinterpret_cast<uint2*>(dst)     = o0;
        *reinterpret_cast<uint2*>(dst + 4) = o1;
        *reinterpret_cast<uint2*>(dst + 8) = o2;
    }
}

// ------------------------------------------------------------------
// Stage a 32-col x 768-K strip of f32 W (k-major) into LDS as bf16,
// XOR-swizzled per 64-k chunk.
// ------------------------------------------------------------------
__device__ __forceinline__
void stage_W(const float* __restrict__ W, int ldw, int wKoff, int n0,
             u16* __restrict__ Ws, int nthreads)
{
    int t = threadIdx.x;
    for (int idx = t; idx < 768 * 8; idx += nthreads) {
        int n4 = (idx & 7) << 2;
        int k  = idx >> 3;
        float4 wv = *reinterpret_cast<const float4*>(
            W + (size_t)(wKoff + k) * ldw + n0 + n4);
        int c = (k >> 3) & 7, kl = k & 7;
        int chbase = (k >> 6) * 2048;
        float wa[4] = {wv.x, wv.y, wv.z, wv.w};
        #pragma unroll
        for (int i = 0; i < 4; ++i) {
            int n = n4 + i;
            Ws[chbase + n * 64 + (kl | ((c ^ (n & 7)) << 3))] = f2bf(wa[i]);
        }
    }
}

// ------------------------------------------------------------------
// Layer-1 GEMM: barrier-free main loop. 288 blocks:
//   blocks 0..191  = L-part, 96 strips x 2 interleaved M-halves
//   blocks 192..287 = R-part, 96 strips
// W strip staged once to LDS; waves independently sweep 64-row tiles,
// A direct global->reg (bf16 compact, L2-resident).
// ------------------------------------------------------------------
__global__ __launch_bounds__(512)
void k_gemm1(const u16* __restrict__ Abf,
             const int* __restrict__ listB, const int* __restrict__ mapC,
             const float* __restrict__ Wl1, const float* __restrict__ Wr1,
             const float* __restrict__ bl1, const float* __restrict__ br1,
             u16* __restrict__ XL1, u16* __restrict__ XR1,
             const int* __restrict__ cnt, int capC, int capB)
{
    __shared__ __align__(16) u16 Ws[12 * 2048];   // 48 KB
    int blk = blockIdx.x;            // 0..287
    bool isR = blk >= 192;
    int strip, half;
    if (isR) { strip = blk - 192; half = 0; }
    else     { strip = blk >> 1;  half = blk & 1; }
    int n0 = strip * 32;
    const float* W    = isR ? Wr1 : Wl1;
    const float* bias = isR ? br1 : bl1;
    u16* Cout = isR ? XR1 : XL1;
    int nC = imin(cnt[1], capC);
    int M  = isR ? imin(cnt[0], capB) : nC;

    stage_W(W, 3072, 0, n0, Ws, 512);
    __syncthreads();

    int t = threadIdx.x;
    int wave = t >> 6, lane = t & 63;
    int lrow = lane & 15, lhi = lane >> 4;
    int x0 = lrow & 7;
    int preB0 = lrow * 64;
    int preB1 = (16 + lrow) * 64;

    float bv0 = bias[n0 + lrow];
    float bv1 = bias[n0 + 16 + lrow];

    // L: interleaved 2-way M-split (rt = 2*wave+half, step 16)
    // R: full sweep (rt = wave, step 8)
    int rt0   = isR ? wave : 2 * wave + half;
    int rtStep = isR ? 8 : 16;

    int ntiles = (M + 63) >> 6;
    for (int rt = rt0; rt < ntiles; rt += rtStep) {
        const u16* ap0; const u16* ap1; const u16* ap2; const u16* ap3;
        {
            int ar0 = rt * 64 + lrow;       if (ar0 >= M) ar0 = M - 1;
            int ar1 = ar0 + 16;             if (ar1 >= M) ar1 = M - 1;
            int ar2 = rt * 64 + 32 + lrow;  if (ar2 >= M) ar2 = M - 1;
            int ar3 = ar2 + 16;             if (ar3 >= M) ar3 = M - 1;
            int g0 = ar0, g1 = ar1, g2 = ar2, g3 = ar3;
            if (isR) {
                g0 = mapC[listB[ar0]]; if (g0 < 0) g0 = 0; if (g0 >= nC) g0 = nC - 1;
                g1 = mapC[listB[ar1]]; if (g1 < 0) g1 = 0; if (g1 >= nC) g1 = nC - 1;
                g2 = mapC[listB[ar2]]; if (g2 < 0) g2 = 0; if (g2 >= nC) g2 = nC - 1;
                g3 = mapC[listB[ar3]]; if (g3 < 0) g3 = 0; if (g3 >= nC) g3 = nC - 1;
            }
            ap0 = Abf + (size_t)g0 * 768 + lhi * 8;
            ap1 = Abf + (size_t)g1 * 768 + lhi * 8;
            ap2 = Abf + (size_t)g2 * 768 + lhi * 8;
            ap3 = Abf + (size_t)g3 * 768 + lhi * 8;
        }

        f32x4 acc00 = {0,0,0,0}, acc01 = {0,0,0,0};
        f32x4 acc10 = {0,0,0,0}, acc11 = {0,0,0,0};
        f32x4 acc20 = {0,0,0,0}, acc21 = {0,0,0,0};
        f32x4 acc30 = {0,0,0,0}, acc31 = {0,0,0,0};

        #pragma unroll 4
        for (int kst = 0; kst < 24; ++kst) {
            int ch = kst >> 1;
            int sw = ((((kst & 1) << 2) | lhi) ^ x0) << 3;
            bf16x8 b0 = *reinterpret_cast<const bf16x8*>(&Ws[ch * 2048 + preB0 + sw]);
            bf16x8 b1 = *reinterpret_cast<const bf16x8*>(&Ws[ch * 2048 + preB1 + sw]);
            bf16x8 a0 = *reinterpret_cast<const bf16x8*>(ap0 + kst * 32);
            bf16x8 a1 = *reinterpret_cast<const bf16x8*>(ap1 + kst * 32);
            bf16x8 a2 = *reinterpret_cast<const bf16x8*>(ap2 + kst * 32);
            bf16x8 a3 = *reinterpret_cast<const bf16x8*>(ap3 + kst * 32);
            acc00 = __builtin_amdgcn_mfma_f32_16x16x32_bf16(a0, b0, acc00, 0, 0, 0);
            acc01 = __builtin_amdgcn_mfma_f32_16x16x32_bf16(a0, b1, acc01, 0, 0, 0);
            acc10 = __builtin_amdgcn_mfma_f32_16x16x32_bf16(a1, b0, acc10, 0, 0, 0);
            acc11 = __builtin_amdgcn_mfma_f32_16x16x32_bf16(a1, b1, acc11, 0, 0, 0);
            acc20 = __builtin_amdgcn_mfma_f32_16x16x32_bf16(a2, b0, acc20, 0, 0, 0);
            acc21 = __builtin_amdgcn_mfma_f32_16x16x32_bf16(a2, b1, acc21, 0, 0, 0);
            acc30 = __builtin_amdgcn_mfma_f32_16x16x32_bf16(a3, b0, acc30, 0, 0, 0);
            acc31 = __builtin_amdgcn_mfma_f32_16x16x32_bf16(a3, b1, acc31, 0, 0, 0);
        }

        int gc0 = n0 + lrow, gc1 = n0 + 16 + lrow;
        #pragma unroll
        for (int j = 0; j < 4; ++j) {
            int r0 = rt * 64 + lhi * 4 + j;
            int r1 = r0 + 16, r2 = r0 + 32, r3 = r0 + 48;
            if (r0 < M) {
                Cout[(size_t)r0 * 3072 + gc0] = f2bf(acc00[j] + bv0);
                Cout[(size_t)r0 * 3072 + gc1] = f2bf(acc01[j] + bv1);
            }
            if (r1 < M) {
                Cout[(size_t)r1 * 3072 + gc0] = f2bf(acc10[j] + bv0);
                Cout[(size_t)r1 * 3072 + gc1] = f2bf(acc11[j] + bv1);
            }
            if (r2 < M) {
                Cout[(size_t)r2 * 3072 + gc0] = f2bf(acc20[j] + bv0);
                Cout[(size_t)r2 * 3072 + gc1] = f2bf(acc21[j] + bv1);
            }
            if (r3 < M) {
                Cout[(size_t)r3 * 3072 + gc0] = f2bf(acc30[j] + bv0);
                Cout[(size_t)r3 * 3072 + gc1] = f2bf(acc31[j] + bv1);
            }
        }
    }
}

// ------------------------------------------------------------------
// Layer-2 GEMM: grid = 48 col-strips x NZ2 k-windows (r12-proven).
// ------------------------------------------------------------------
__global__ __launch_bounds__(256)
void k_gemm2(const u16* __restrict__ H1bf,
             const float* __restrict__ Wl2, const float* __restrict__ Wr2,
             float* __restrict__ XLR2,
             const int* __restrict__ cnt, int capB)
{
    __shared__ __align__(16) u16 Ws[12 * 2048];
    int strip = blockIdx.x;
    int z = blockIdx.z;
    int n0g = strip * 32;
    bool hi = n0g >= 768;
    const float* W = hi ? Wr2 : Wl2;
    int n0w = hi ? n0g - 768 : n0g;
    int nB = imin(cnt[0], capB);
    float* Cp = XLR2 + (size_t)z * capB * 1536;

    stage_W(W, 768, z * 768, n0w, Ws, 256);
    __syncthreads();

    int t = threadIdx.x;
    int wave = t >> 6, lane = t & 63;
    int lrow = lane & 15, lhi = lane >> 4;
    int x0 = lrow & 7;
    int preB0 = lrow * 64, preB1 = (16 + lrow) * 64;

    int ntiles = (nB + 31) >> 5;
    for (int rt = wave; rt < ntiles; rt += 4) {
        int ar0 = rt * 32 + lrow;  if (ar0 >= nB) ar0 = nB - 1;
        int ar1 = ar0 + 16;        if (ar1 >= nB) ar1 = nB - 1;
        const u16* ap0 = H1bf + (size_t)ar0 * 3072 + z * 768 + lhi * 8;
        const u16* ap1 = H1bf + (size_t)ar1 * 3072 + z * 768 + lhi * 8;

        f32x4 acc00 = {0,0,0,0}, acc01 = {0,0,0,0};
        f32x4 acc10 = {0,0,0,0}, acc11 = {0,0,0,0};

        #pragma unroll 4
        for (int kst = 0; kst < 24; ++kst) {
            int ch = kst >> 1;
            int sw = ((((kst & 1) << 2) | lhi) ^ x0) << 3;
            bf16x8 b0 = *reinterpret_cast<const bf16x8*>(&Ws[ch * 2048 + preB0 + sw]);
            bf16x8 b1 = *reinterpret_cast<const bf16x8*>(&Ws[ch * 2048 + preB1 + sw]);
            bf16x8 a0 = *reinterpret_cast<const bf16x8*>(ap0 + kst * 32);
            bf16x8 a1 = *reinterpret_cast<const bf16x8*>(ap1 + kst * 32);
            acc00 = __builtin_amdgcn_mfma_f32_16x16x32_bf16(a0, b0, acc00, 0, 0, 0);
            acc01 = __builtin_amdgcn_mfma_f32_16x16x32_bf16(a0, b1, acc01, 0, 0, 0);
            acc10 = __builtin_amdgcn_mfma_f32_16x16x32_bf16(a1, b0, acc10, 0, 0, 0);
            acc11 = __builtin_amdgcn_mfma_f32_16x16x32_bf16(a1, b1, acc11, 0, 0, 0);
        }

        int gc0 = n0g + lrow, gc1 = n0g + 16 + lrow;
        #pragma unroll
        for (int j = 0; j < 4; ++j) {
            int r0 = rt * 32 + lhi * 4 + j;
            int r1 = r0 + 16;
            if (r0 < nB) {
                Cp[(size_t)r0 * 1536 + gc0] = acc00[j];
                Cp[(size_t)r0 * 1536 + gc1] = acc01[j];
            }
            if (r1 < nB) {
                Cp[(size_t)r1 * 1536 + gc0] = acc10[j];
                Cp[(size_t)r1 * 1536 + gc1] = acc11[j];
            }
        }
    }
}

// ------------------------------------------------------------------
// Fused layer-1 edge phase: one block per B node, 4 waves = 4 heads.
// ------------------------------------------------------------------
__global__ __launch_bounds__(256)
void k_fused1(const u16* __restrict__ XL1, const u16* __restrict__ XR1,
              const float* __restrict__ att1, const float* __restrict__ bias1,
              const int* __restrict__ mapC,
              const int* __restrict__ deg1, const int* __restrict__ e1bin,
              u16* __restrict__ H1bf,
              const int* __restrict__ cnt, int capB, int capC)
{
    __shared__ int sIdx[BINW];
    int b = blockIdx.x;
    int nB = cnt[0]; if (nB > capB) nB = capB;
    if (b >= nB) return;
    int t = threadIdx.x;
    int n = deg1[b]; if (n > BINW) n = BINW;
    if (t < n) {
        int c = mapC[e1bin[b * BINW + t]];
        if (c < 0) c = 0; if (c >= capC) c = capC - 1;
        sIdx[t] = c;
    }
    __syncthreads();

    int base = t * 12;
    float xr[12], av[12];
    {
        const u16* p = XR1 + (size_t)b * 3072 + base;
        uint2 q0 = *reinterpret_cast<const uint2*>(p);
        uint2 q1 = *reinterpret_cast<const uint2*>(p + 4);
        uint2 q2 = *reinterpret_cast<const uint2*>(p + 8);
        u32 w[6] = {q0.x, q0.y, q1.x, q1.y, q2.x, q2.y};
        #pragma unroll
        for (int j = 0; j < 6; ++j) {
            xr[2*j]   = bf2f((u16)(w[j] & 0xFFFF));
            xr[2*j+1] = bf2f((u16)(w[j] >> 16));
        }
        float4 a0 = *reinterpret_cast<const float4*>(att1 + base);
        float4 a1 = *reinterpret_cast<const float4*>(att1 + base + 4);
        float4 a2 = *reinterpret_cast<const float4*>(att1 + base + 8);
        av[0]=a0.x; av[1]=a0.y; av[2]=a0.z; av[3]=a0.w;
        av[4]=a1.x; av[5]=a1.y; av[6]=a1.z; av[7]=a1.w;
        av[8]=a2.x; av[9]=a2.y; av[10]=a2.z; av[11]=a2.w;
    }

    float acc[12];
    #pragma unroll
    for (int j = 0; j < 12; ++j) acc[j] = 0.f;
    float sumex = 0.f;

    uint2 q0, q1, q2;
    if (n > 0) {
        const u16* p = XL1 + (size_t)sIdx[0] * 3072 + base;
        q0 = *reinterpret_cast<const uint2*>(p);
        q1 = *reinterpret_cast<const uint2*>(p + 4);
        q2 = *reinterpret_cast<const uint2*>(p + 8);
    }
    for (int i = 0; i < n; ++i) {
        uint2 r0 = q0, r1 = q1, r2 = q2;
        if (i + 1 < n) {
            const u16* p = XL1 + (size_t)sIdx[i + 1] * 3072 + base;
            q0 = *reinterpret_cast<const uint2*>(p);
            q1 = *reinterpret_cast<const uint2*>(p + 4);
            q2 = *reinterpret_cast<const uint2*>(p + 8);
        }
        float xl[12];
        u32 w[6] = {r0.x, r0.y, r1.x, r1.y, r2.x, r2.y};
        #pragma unroll
        for (int j = 0; j < 6; ++j) {
            xl[2*j]   = bf2f((u16)(w[j] & 0xFFFF));
            xl[2*j+1] = bf2f((u16)(w[j] >> 16));
        }
        float pa = 0.f;
        #pragma unroll
        for (int j = 0; j < 12; ++j)
            pa = fmaf(av[j], lrelu(xl[j] + xr[j]), pa);
        #pragma unroll
        for (int off = 32; off > 0; off >>= 1) pa += __shfl_xor(pa, off);
        float ex = expf(pa);
        sumex += ex;
        #pragma unroll
        for (int j = 0; j < 12; ++j) acc[j] = fmaf(ex, xl[j], acc[j]);
    }

    float inv = 1.f / (sumex + 1e-16f);
    u32 o[6];
    #pragma unroll
    for (int j = 0; j < 6; ++j) {
        float v0 = acc[2*j]   * inv + bias1[base + 2*j];
        float v1 = acc[2*j+1] * inv + bias1[base + 2*j+1];
        v0 = v0 > 0.f ? v0 : 0.f;
        v1 = v1 > 0.f ? v1 : 0.f;
        o[j] = (u32)f2bf(v0) | ((u32)f2bf(v1) << 16);
    }
    u16* q = H1bf + (size_t)b * 3072 + base;
    uint2 s0; s0.x = o[0]; s0.y = o[1];
    uint2 s1; s1.x = o[2]; s1.y = o[3];
    uint2 s2; s2.x = o[4]; s2.y = o[5];
    *reinterpret_cast<uint2*>(q)     = s0;
    *reinterpret_cast<uint2*>(q + 4) = s1;
    *reinterpret_cast<uint2*>(q + 8) = s2;
}

// ------------------------------------------------------------------
// Fused layer-2 edge phase: one block per pathology node, 4 waves split
// edges, LDS combine. Sums NZ2 K-partials + folded biases. Writes d_out.
// ------------------------------------------------------------------
__global__ __launch_bounds__(256)
void k_fused2(const float* __restrict__ XLR2,
              const float* __restrict__ att2, const float* __restrict__ bias2,
              const float* __restrict__ bl2, const float* __restrict__ br2,
              const int* __restrict__ mapB,
              const int* __restrict__ deg2, const int* __restrict__ e2bin,
              float* __restrict__ out, int capB)
{
    __shared__ int sIdx[BINW];
    __shared__ float sAcc[4][768];
    __shared__ float sSum[4];
    const size_t PART = (size_t)capB * 1536;
    int a = blockIdx.x;
    int t = threadIdx.x;
    int wv = t >> 6, lane = t & 63;
    int n = deg2[a]; if (n > BINW) n = BINW;
    if (t < n) {
        int bs = mapB[e2bin[a * BINW + t]];
        if (bs < 0) bs = 0; if (bs >= capB) bs = capB - 1;
        sIdx[t] = bs;
    }
    __syncthreads();

    int base = lane * 12;
    int bd = mapB[a];
    if (bd < 0) bd = 0; if (bd >= capB) bd = capB - 1;

    float xr[12], av[12], blv[12];
    {
        const float* p = XLR2 + (size_t)bd * 1536 + 768 + base;
        #pragma unroll
        for (int j = 0; j < 12; ++j) xr[j] = br2[base + j];
        for (int z = 0; z < NZ2; ++z)
            #pragma unroll
            for (int j = 0; j < 12; ++j) xr[j] += p[z * PART + j];
        #pragma unroll
        for (int j = 0; j < 12; ++j) { av[j] = att2[base + j]; blv[j] = bl2[base + j]; }
    }

    float acc[12];
    #pragma unroll
    for (int j = 0; j < 12; ++j) acc[j] = 0.f;
    float sumex = 0.f;

    for (int i = wv; i < n; i += 4) {
        int bs = sIdx[i];
        const float* p = XLR2 + (size_t)bs * 1536 + base;
        float xl[12];
        #pragma unroll
        for (int j = 0; j < 12; ++j) xl[j] = blv[j];
        for (int z = 0; z < NZ2; ++z)
            #pragma unroll
            for (int j = 0; j < 12; ++j) xl[j] += p[z * PART + j];
        float pa = 0.f;
        #pragma unroll
        for (int j = 0; j < 12; ++j)
            pa = fmaf(av[j], lrelu(xl[j] + xr[j]), pa);
        #pragma unroll
        for (int off = 32; off > 0; off >>= 1) pa += __shfl_xor(pa, off);
        float ex = expf(pa);
        sumex += ex;
        #pragma unroll
        for (int j = 0; j < 12; ++j) acc[j] = fmaf(ex, xl[j], acc[j]);
    }

    if (lane == 0) sSum[wv] = sumex;
    #pragma unroll
    for (int j = 0; j < 12; ++j) sAcc[wv][base + j] = acc[j];
    __syncthreads();

    float tot = sSum[0] + sSum[1] + sSum[2] + sSum[3];
    float inv = 1.f / (tot + 1e-16f);
    for (int c = t; c < 768; c += 256) {
        float s = sAcc[0][c] + sAcc[1][c] + sAcc[2][c] + sAcc[3][c];
        out[(size_t)a * 768 + c] = s * inv + bias2[c];
    }
}

// ------------------------------------------------------------------
// Host side
// ------------------------------------------------------------------
struct Lay {
    size_t mapB, mapC;
    size_t zbase, zbytes;
    size_t cnt, deg2, deg1;
    size_t listB, e1bin, e2bin;
    size_t Abf, XL1, XR1, H1bf, XLR2;
    size_t total;
};

static Lay makeLayout(int Nn, int cB, int cC)
{
    Lay L{};
    size_t off = 0;
    auto take = [&](size_t bytes) { size_t o = (off + 255) & ~(size_t)255; off = o + bytes; return o; };
    L.mapB = take((size_t)2 * Nn * 4);
    L.mapC = L.mapB + (size_t)Nn * 4;
    size_t zo = 0;
    size_t cntO  = zo; zo += 64;
    size_t deg2O = zo; zo += 64 * 4;
    size_t deg1O = zo; zo += (size_t)cB * 4;
    L.zbase = take(zo); L.zbytes = zo;
    L.cnt  = L.zbase + cntO;
    L.deg2 = L.zbase + deg2O;
    L.deg1 = L.zbase + deg1O;
    L.listB = take((size_t)cB * 4);
    L.e1bin = take((size_t)cB * BINW * 4);
    L.e2bin = take((size_t)16 * BINW * 4);
    L.Abf  = take((size_t)cC * 768 * 2);
    L.XL1  = take((size_t)cC * 3072 * 2);
    L.XR1  = take((size_t)cB * 3072 * 2);
    L.H1bf = take((size_t)cB * 3072 * 2);
    L.XLR2 = take((size_t)NZ2 * cB * 1536 * 4);
    L.total = off;
    return L;
}

extern "C" void kernel_launch(void* const* d_in, const int* in_sizes, int n_in,
                              void* d_out, int out_size, void* d_ws, size_t ws_size,
                              hipStream_t stream)
{
    const float* x     = (const float*)d_in[0];
    const int*   ei    = (const int*)  d_in[1];
    const float* Wl1   = (const float*)d_in[2];
    const float* bl1   = (const float*)d_in[3];
    const float* Wr1   = (const float*)d_in[4];
    const float* br1   = (const float*)d_in[5];
    const float* att1  = (const float*)d_in[6];
    const float* bias1 = (const float*)d_in[7];
    const float* Wl2   = (const float*)d_in[8];
    const float* bl2   = (const float*)d_in[9];
    const float* Wr2   = (const float*)d_in[10];
    const float* br2   = (const float*)d_in[11];
    const float* att2  = (const float*)d_in[12];
    const float* bias2 = (const float*)d_in[13];
    float* out = (float*)d_out;

    int Nn = in_sizes[0] / 768;
    int E  = in_sizes[1] / 2;
    const int* esrc = ei;
    const int* edst = ei + E;
    int ET = E + Nn;

    static const int tiers[2][2] = { {256, 1024}, {128, 768} };
    int capB = tiers[1][0], capC = tiers[1][1];
    Lay L = makeLayout(Nn, capB, capC);
    for (int t = 0; t < 2; ++t) {
        Lay cand = makeLayout(Nn, tiers[t][0], tiers[t][1]);
        if (cand.total <= ws_size) { capB = tiers[t][0]; capC = tiers[t][1]; L = cand; break; }
    }

    char* ws = (char*)d_ws;
    int*   mapB  = (int*)  (ws + L.mapB);
    int*   mapC  = (int*)  (ws + L.mapC);
    int*   cnt   = (int*)  (ws + L.cnt);
    int*   deg2  = (int*)  (ws + L.deg2);
    int*   deg1  = (int*)  (ws + L.deg1);
    int*   listB = (int*)  (ws + L.listB);
    int*   e1bin = (int*)  (ws + L.e1bin);
    int*   e2bin = (int*)  (ws + L.e2bin);
    u16*   Abf   = (u16*)  (ws + L.Abf);
    u16*   XL1   = (u16*)  (ws + L.XL1);
    u16*   XR1   = (u16*)  (ws + L.XR1);
    u16*   H1bf  = (u16*)  (ws + L.H1bf);
    float* XLR2  = (float*)(ws + L.XLR2);

    k_init<<<256, 256, 0, stream>>>((int*)(ws + L.mapB), 2 * Nn,
                                    (u32*)(ws + L.zbase), (int)(L.zbytes / 4));

    int bgrid = (ET + 255) / 256;
    k_build2<<<bgrid, 256, 0, stream>>>(esrc, edst, E, Nn, mapB, listB, cnt,
                                        deg2, e2bin, capB);
    k_build1<<<bgrid, 256, 0, stream>>>(esrc, edst, E, Nn, x, mapB, mapC, cnt,
                                        deg1, e1bin, Abf, capB, capC);

    k_gemm1<<<288, 512, 0, stream>>>(Abf, listB, mapC, Wl1, Wr1, bl1, br1,
                                     XL1, XR1, cnt, capC, capB);

    k_fused1<<<capB, 256, 0, stream>>>(XL1, XR1, att1, bias1, mapC, deg1, e1bin,
                                       H1bf, cnt, capB, capC);

    k_gemm2<<<dim3(48, 1, NZ2), 256, 0, stream>>>(H1bf, Wl2, Wr2, XLR2, cnt, capB);

    k_fused2<<<N_PATH, 256, 0, stream>>>(XLR2, att2, bias2, bl2, br2, mapB,
                                         deg2, e2bin, out, capB);
}